// Round 6
// baseline (676.217 us; speedup 1.0000x reference)
//
#include <hip/hip_runtime.h>
#include <math.h>

#define NP 256   // datapoints
#define BB 128   // batch
#define DD 784   // dims
#define HS_MIN 1e-7f
#define LOG_HS_MIN -16.11809565095832f   // log(1e-7)
#define LOG_MB -16.811242831518264f      // log(5e-8) — mask bound in log space
#define NEG_HALF_LOG_2PI -0.9189385332046727f
#define W 16     // householder window
#define NW 49    // 784/16
#define BK 4     // batch rows per thread in k_main

// ---------------- ndtri (AS241, double poly) from log_cdf / log_sf ----------------
// Round-3 form: double exp() for the mid branch (d ndtri/dp ~ 8e6 near the mask
// boundary — f32 __expf noise there cost ~0.8 absmax; do NOT "optimize" this).
__device__ double ndtri_logs(float log_cdf_f, float log_sf_f) {
    double lp = (double)log_cdf_f;
    double ls = (double)log_sf_f;
    double p = exp(lp);
    double q = p - 0.5;
    if (fabs(q) <= 0.425) {
        double r = 0.180625 - q * q;
        double num = (((((((2.5090809287301226727e3 * r + 3.3430575583588128105e4) * r
                         + 6.7265770927008700853e4) * r + 4.5921953931549871457e4) * r
                         + 1.3731693765509461125e4) * r + 1.9715909503065514427e3) * r
                         + 1.3314166789178437745e2) * r + 3.3871328727963666080e0);
        double den = (((((((5.2264952788528545610e3 * r + 2.8729085735721942674e4) * r
                         + 3.9307895800092710610e4) * r + 2.1213794301586595867e4) * r
                         + 5.3941960214247511077e3) * r + 6.8718700749205790830e2) * r
                         + 4.2313330701600911252e1) * r + 1.0);
        return q * num / den;
    }
    double r = (q < 0.0) ? sqrt(-lp) : sqrt(-ls);
    double v;
    if (r <= 5.0) {
        r -= 1.6;
        double num = (((((((7.74545014278341407640e-4 * r + 2.27238449892691845833e-2) * r
                         + 2.41780725177450611770e-1) * r + 1.27045825245236838258e0) * r
                         + 3.64784832476320460504e0) * r + 5.76949722146069140550e0) * r
                         + 4.63033784615654529590e0) * r + 1.42343711074968357734e0);
        double den = (((((((1.05075007164441684324e-9 * r + 5.47593808499534494600e-4) * r
                         + 1.51986665636164571966e-2) * r + 1.48103976427480074590e-1) * r
                         + 6.89767334985100004550e-1) * r + 1.67638483018380384940e0) * r
                         + 2.05319162663775882187e0) * r + 1.0);
        v = num / den;
    } else {
        r -= 5.0;
        double num = (((((((2.01033439929228813265e-7 * r + 2.71155556874348757815e-5) * r
                         + 1.24266094738807843860e-3) * r + 2.65321895265761230930e-2) * r
                         + 2.96560571828504891230e-1) * r + 1.78482653991729133580e0) * r
                         + 5.46378491116411436990e0) * r + 6.65790464350110377720e0);
        double den = (((((((2.04426310338993978564e-15 * r + 1.42151175831644588870e-7) * r
                         + 1.84631831751005468180e-5) * r + 7.86869131145613259100e-4) * r
                         + 1.48753612908506148525e-2) * r + 1.36929880922735805310e-1) * r
                         + 5.99832206555887937690e-1) * r + 1.0);
        v = num / den;
    }
    return (q < 0.0) ? -v : v;
}

// ---------------- K0: lsew[d] = logsumexp_n kde_weights[n,d] (block per d) ----------------
__global__ __launch_bounds__(256) void k_lsew(const float* __restrict__ kw,
                                              float* __restrict__ lsew) {
    __shared__ float red[4];
    int d = blockIdx.x;
    int n = threadIdx.x;          // NP == 256 == blockDim
    float a = kw[n * DD + d];
    float m = a;
    #pragma unroll
    for (int off = 32; off; off >>= 1) m = fmaxf(m, __shfl_xor(m, off, 64));
    if ((threadIdx.x & 63) == 0) red[threadIdx.x >> 6] = m;
    __syncthreads();
    m = fmaxf(fmaxf(red[0], red[1]), fmaxf(red[2], red[3]));
    __syncthreads();
    float e = __expf(a - m);
    #pragma unroll
    for (int off = 32; off; off >>= 1) e += __shfl_xor(e, off, 64);
    if ((threadIdx.x & 63) == 0) red[threadIdx.x >> 6] = e;
    __syncthreads();
    if (threadIdx.x == 0)
        lsew[d] = m + __logf(red[0] + red[1] + red[2] + red[3]);
}

// ---------------- K1: per-(n,d) precompute, packed float4 {dp, 1/hs, w, w-lhc} ----------------
__global__ __launch_bounds__(256) void k_prep(const float* __restrict__ kw,
                                              const float* __restrict__ log_hs,
                                              const float* __restrict__ dp,
                                              const float* __restrict__ lsew,
                                              float4* __restrict__ pk) {
    int n = blockIdx.x;
    for (int d = threadIdx.x; d < DD; d += 256) {
        int idx = n * DD + d;
        float lh = log_hs[idx];
        float hs = fmaxf(__expf(lh), HS_MIN);
        float lhc = fmaxf(lh, LOG_HS_MIN);
        float wv = kw[idx] - lsew[d];
        pk[idx] = make_float4(dp[idx], 1.f / hs, wv, wv - lhc);
    }
}

// ---------------- K2: main KDE + inverse + term (BK batch rows / thread) ----------------
__global__ __launch_bounds__(128) void k_main(const float* __restrict__ x,
                                              const float4* __restrict__ pk,
                                              float* __restrict__ Y,
                                              float* __restrict__ T) {
    int g = blockIdx.x * 128 + threadIdx.x;        // g < (BB/BK)*DD exactly
    int d = g % DD;
    int b0 = (g / DD) * BK;
    float xv[BK], m1[BK], s1[BK], m2[BK], s2[BK], m3[BK], s3[BK];
    #pragma unroll
    for (int i = 0; i < BK; ++i) {
        xv[i] = x[(b0 + i) * DD + d];
        m1[i] = -INFINITY; s1[i] = 0.f;
        m2[i] = -INFINITY; s2[i] = 0.f;
        m3[i] = -INFINITY; s3[i] = 0.f;
    }
    for (int n = 0; n < NP; ++n) {
        float4 c = pk[n * DD + d];          // {dp, ihs, w, w-lhc}
        #pragma unroll
        for (int i = 0; i < BK; ++i) {
            float u = (c.x - xv[i]) * c.y;
            float e = __expf(-fabsf(u));
            float l1p = __logf(1.f + e);
            float sp = fmaxf(u, 0.f) + l1p;
            float a1 = c.z - sp;
            float a2 = fminf(u, 0.f) - l1p + c.z;
            float a3 = u - 2.f * sp + c.w;
            // 1-exp online LSE update — bit-identical to the 2-exp form
            float d1 = a1 - m1[i]; float E1 = __expf(-fabsf(d1));
            s1[i] = (d1 <= 0.f) ? (s1[i] + E1) : (s1[i] * E1 + 1.f);
            m1[i] = fmaxf(m1[i], a1);
            float d2 = a2 - m2[i]; float E2 = __expf(-fabsf(d2));
            s2[i] = (d2 <= 0.f) ? (s2[i] + E2) : (s2[i] * E2 + 1.f);
            m2[i] = fmaxf(m2[i], a2);
            float d3 = a3 - m3[i]; float E3 = __expf(-fabsf(d3));
            s3[i] = (d3 <= 0.f) ? (s3[i] + E3) : (s3[i] * E3 + 1.f);
            m3[i] = fmaxf(m3[i], a3);
        }
    }
    #pragma unroll
    for (int i = 0; i < BK; ++i) {
        float log_cdf = m1[i] + __logf(s1[i]);
        float log_sf  = m2[i] + __logf(s2[i]);
        float log_pdf = m3[i] + __logf(s3[i]);
        bool right = (log_sf  <= LOG_MB);
        bool left  = (log_cdf <= LOG_MB);
        float inv, lgd;
        if (right) {
            float t2 = -2.f * log_sf;
            inv = sqrtf(t2);
            lgd = 0.5f * __logf(t2) - log_sf;
        } else if (left) {
            float t2 = -2.f * log_cdf;
            inv = -sqrtf(t2);
            lgd = 0.5f * __logf(t2) - log_cdf;
        } else {
            inv = (float)ndtri_logs(log_cdf, log_sf);
            lgd = -0.5f * inv * inv + NEG_HALF_LOG_2PI;
        }
        Y[(b0 + i) * DD + d] = inv;
        T[(b0 + i) * DD + d] = log_pdf - lgd;
    }
}

// ---------------- K3: log_det reduction ----------------
__global__ __launch_bounds__(256) void k_logdet(const float* __restrict__ T,
                                                const float* __restrict__ ld_in,
                                                float* __restrict__ out) {
    __shared__ float red[4];
    int b = blockIdx.x;
    float s = 0.f;
    for (int d = threadIdx.x; d < DD; d += 256) s += T[b * DD + d];
    #pragma unroll
    for (int off = 32; off; off >>= 1) s += __shfl_down(s, off, 64);
    if ((threadIdx.x & 63) == 0) red[threadIdx.x >> 6] = s;
    __syncthreads();
    if (threadIdx.x == 0) out[BB * DD + b] = ld_in[b] + red[0] + red[1] + red[2] + red[3];
}

// ---------------- K4: normalize reflector rows ----------------
__global__ __launch_bounds__(256) void k_vn(const float* __restrict__ vs,
                                            float* __restrict__ vn) {
    __shared__ float red[4];
    int i = blockIdx.x;
    float ss = 0.f;
    for (int j = threadIdx.x; j < DD; j += 256) {
        float v = vs[i * DD + j];
        ss += v * v;
    }
    #pragma unroll
    for (int off = 32; off; off >>= 1) ss += __shfl_down(ss, off, 64);
    if ((threadIdx.x & 63) == 0) red[threadIdx.x >> 6] = ss;
    __syncthreads();
    float inorm = rsqrtf(red[0] + red[1] + red[2] + red[3]);
    for (int j = threadIdx.x; j < DD; j += 256)
        vn[i * DD + j] = vs[i * DD + j] * inorm;
}

// ---------------- K5: Gram of each 16-reflector window ----------------
__global__ __launch_bounds__(256) void k_gram(const float* __restrict__ vn,
                                              float* __restrict__ G) {
    int wi = blockIdx.x;
    int t = threadIdx.x;
    int k = t >> 4, i = t & 15;
    const float4* a = (const float4*)(vn + (wi * W + k) * DD);
    const float4* b = (const float4*)(vn + (wi * W + i) * DD);
    float s = 0.f;
    for (int j = 0; j < DD / 4; ++j) {
        float4 av = a[j], bv = b[j];
        s += av.x * bv.x + av.y * bv.y + av.z * bv.z + av.w * bv.w;
    }
    G[wi * 256 + k * 16 + i] = s;   // G[w][k][i] = v_k . v_i
}

// ---------------- K6: windowed-WY Householder chain ----------------
// ROUND-3 compute logic VERBATIM (strided ownership, butterfly reduce, wv0-only
// substitution via s2s LDS, Gcol from global). SINGLE delta vs the green round-3
// kernel: V window read from LDS Vl (staged via float4 regs -> ds_write, single
// buffer) instead of per-window global re-reads. No register V arrays -> no
// spills (round 3 spilled at VGPR_Count=132 and ran 240us latency-bound).
__global__ __launch_bounds__(256, 1) void k_house(const float* __restrict__ Yin,
                                                  const float* __restrict__ VN,
                                                  const float* __restrict__ G,
                                                  float* __restrict__ out) {
    __shared__ __align__(16) float Vl[W * DD];   // 50176 B
    __shared__ float red[4 * W];
    __shared__ float s2s[W];
    const int b = blockIdx.x;
    const int tid = threadIdx.x;
    const int lane = tid & 63;
    const int wv = tid >> 6;
    const bool has3 = (tid < DD - 3 * 256);   // 16 threads own a 4th element

    float y0 = Yin[b * DD + tid];
    float y1 = Yin[b * DD + tid + 256];
    float y2 = Yin[b * DD + tid + 512];
    float y3 = has3 ? Yin[b * DD + tid + 768] : 0.f;

    float4 sv[13];
    // stage window 0: Vl[j] = VN[j] for j < W*DD
    #pragma unroll
    for (int k = 0; k < 12; ++k)
        sv[k] = *(const float4*)(VN + (k * 256 + tid) * 4);
    if (tid < 64) sv[12] = *(const float4*)(VN + (3072 + tid) * 4);
    #pragma unroll
    for (int k = 0; k < 12; ++k)
        *(float4*)(&Vl[(k * 256 + tid) * 4]) = sv[k];
    if (tid < 64) *(float4*)(&Vl[(3072 + tid) * 4]) = sv[12];
    __syncthreads();

    for (int wi = 0; wi < NW; ++wi) {
        const bool more = (wi + 1 < NW);
        // issue next window's global loads now; ds_writes happen after the
        // end-of-window barrier, so the latency hides under this window's compute
        if (more) {
            const float* src = VN + (wi + 1) * (W * DD);
            #pragma unroll
            for (int k = 0; k < 12; ++k)
                sv[k] = *(const float4*)(src + (k * 256 + tid) * 4);
            if (tid < 64) sv[12] = *(const float4*)(src + (3072 + tid) * 4);
        }

        // G column for this lane (only wave-0 lanes<16 consume)
        float Gcol[W];
        #pragma unroll
        for (int k = 0; k < W; ++k)
            Gcol[k] = (tid < W) ? G[wi * 256 + k * 16 + tid] : 0.f;

        // partial dots q_r against current y (V from LDS)
        float p[W];
        #pragma unroll
        for (int r = 0; r < W; ++r) {
            float v3 = has3 ? Vl[r * DD + tid + 768] : 0.f;
            p[r] = y0 * Vl[r * DD + tid]
                 + y1 * Vl[r * DD + tid + 256]
                 + y2 * Vl[r * DD + tid + 512]
                 + y3 * v3;
        }

        // wave butterfly reduce (all lanes end with the wave total)
        #pragma unroll
        for (int r = 0; r < W; ++r) {
            #pragma unroll
            for (int off = 32; off; off >>= 1)
                p[r] += __shfl_xor(p[r], off, 64);
        }
        float mine = p[0];
        #pragma unroll
        for (int r = 1; r < W; ++r)
            if (lane == r) mine = p[r];
        if (lane < W) red[wv * W + lane] = mine;
        __syncthreads();

        // wave 0: cross-wave sum + forward substitution s_r = q_r - 2 sum_{k<r} G[k][r] s_k
        if (wv == 0) {
            float acc = 0.f;
            if (lane < W)
                acc = red[lane] + red[W + lane] + red[2 * W + lane] + red[3 * W + lane];
            #pragma unroll
            for (int k = 0; k < W; ++k) {
                float sk = __shfl(acc, k, 64);
                if (lane > k) acc -= 2.f * Gcol[k] * sk;
            }
            if (lane < W) s2s[lane] = 2.f * acc;
        }
        __syncthreads();

        // rank-16 update (V from LDS again — cheap, avoids 64-reg V arrays)
        #pragma unroll
        for (int r = 0; r < W; ++r) {
            float s2 = s2s[r];
            y0 -= s2 * Vl[r * DD + tid];
            y1 -= s2 * Vl[r * DD + tid + 256];
            y2 -= s2 * Vl[r * DD + tid + 512];
            if (has3) y3 -= s2 * Vl[r * DD + tid + 768];
        }
        __syncthreads();   // everyone done reading Vl/s2s/red

        if (more) {
            #pragma unroll
            for (int k = 0; k < 12; ++k)
                *(float4*)(&Vl[(k * 256 + tid) * 4]) = sv[k];
            if (tid < 64) *(float4*)(&Vl[(3072 + tid) * 4]) = sv[12];
            __syncthreads();   // next window resident
        }
    }

    out[b * DD + tid]       = y0;
    out[b * DD + tid + 256] = y1;
    out[b * DD + tid + 512] = y2;
    if (has3) out[b * DD + tid + 768] = y3;
}

// ---------------- launch ----------------
extern "C" void kernel_launch(void* const* d_in, const int* in_sizes, int n_in,
                              void* d_out, int out_size, void* d_ws, size_t ws_size,
                              hipStream_t stream) {
    const float* x      = (const float*)d_in[0];   // [B,D]
    const float* ld_in  = (const float*)d_in[1];   // [B]
    const float* dp     = (const float*)d_in[2];   // [N,D]
    const float* log_hs = (const float*)d_in[3];   // [N,D]
    const float* kw     = (const float*)d_in[4];   // [N,D]
    const float* vs     = (const float*)d_in[5];   // [D,D]
    float* out = (float*)d_out;                    // x_out [B,D] then log_det [B]

    float* ws   = (float*)d_ws;
    float* lsew = ws;                         // 784 (pad to 1024)
    float4* pk  = (float4*)(ws + 1024);       // N*D float4
    float* Y    = ws + 1024 + NP * DD * 4;    // B*D
    float* T    = Y + BB * DD;                // B*D
    float* VN   = T + BB * DD;                // D*D
    float* G    = VN + DD * DD;               // NW*256

    k_lsew<<<DD, 256, 0, stream>>>(kw, lsew);
    k_prep<<<NP, 256, 0, stream>>>(kw, log_hs, dp, lsew, pk);
    k_main<<<(BB / BK) * DD / 128, 128, 0, stream>>>(x, pk, Y, T);
    k_logdet<<<BB, 256, 0, stream>>>(T, ld_in, out);
    k_vn<<<DD, 256, 0, stream>>>(vs, VN);
    k_gram<<<NW, 256, 0, stream>>>(VN, G);
    k_house<<<BB, 256, 0, stream>>>(Y, VN, G, out);
}

// Round 7
// 604.678 us; speedup vs baseline: 1.1183x; 1.1183x over previous
//
#include <hip/hip_runtime.h>
#include <math.h>

#define NP 256   // datapoints
#define BB 128   // batch
#define DD 784   // dims
#define HS_MIN 1e-7f
#define LOG_HS_MIN -16.11809565095832f   // log(1e-7)
#define LOG_MB -16.811242831518264f      // log(5e-8) — mask bound in log space
#define NEG_HALF_LOG_2PI -0.9189385332046727f
#define W 16     // householder window
#define NW 49    // 784/16
#define BK 4     // batch rows per thread in k_main

// ---------------- ndtri (AS241, double poly) from log_cdf / log_sf ----------------
// Double exp() for the mid branch (d ndtri/dp ~ 8e6 near the mask boundary —
// f32 __expf noise there costs ~0.8 absmax; do NOT "optimize" this).
__device__ double ndtri_logs(float log_cdf_f, float log_sf_f) {
    double lp = (double)log_cdf_f;
    double ls = (double)log_sf_f;
    double p = exp(lp);
    double q = p - 0.5;
    if (fabs(q) <= 0.425) {
        double r = 0.180625 - q * q;
        double num = (((((((2.5090809287301226727e3 * r + 3.3430575583588128105e4) * r
                         + 6.7265770927008700853e4) * r + 4.5921953931549871457e4) * r
                         + 1.3731693765509461125e4) * r + 1.9715909503065514427e3) * r
                         + 1.3314166789178437745e2) * r + 3.3871328727963666080e0);
        double den = (((((((5.2264952788528545610e3 * r + 2.8729085735721942674e4) * r
                         + 3.9307895800092710610e4) * r + 2.1213794301586595867e4) * r
                         + 5.3941960214247511077e3) * r + 6.8718700749205790830e2) * r
                         + 4.2313330701600911252e1) * r + 1.0);
        return q * num / den;
    }
    double r = (q < 0.0) ? sqrt(-lp) : sqrt(-ls);
    double v;
    if (r <= 5.0) {
        r -= 1.6;
        double num = (((((((7.74545014278341407640e-4 * r + 2.27238449892691845833e-2) * r
                         + 2.41780725177450611770e-1) * r + 1.27045825245236838258e0) * r
                         + 3.64784832476320460504e0) * r + 5.76949722146069140550e0) * r
                         + 4.63033784615654529590e0) * r + 1.42343711074968357734e0);
        double den = (((((((1.05075007164441684324e-9 * r + 5.47593808499534494600e-4) * r
                         + 1.51986665636164571966e-2) * r + 1.48103976427480074590e-1) * r
                         + 6.89767334985100004550e-1) * r + 1.67638483018380384940e0) * r
                         + 2.05319162663775882187e0) * r + 1.0);
        v = num / den;
    } else {
        r -= 5.0;
        double num = (((((((2.01033439929228813265e-7 * r + 2.71155556874348757815e-5) * r
                         + 1.24266094738807843860e-3) * r + 2.65321895265761230930e-2) * r
                         + 2.96560571828504891230e-1) * r + 1.78482653991729133580e0) * r
                         + 5.46378491116411436990e0) * r + 6.65790464350110377720e0);
        double den = (((((((2.04426310338993978564e-15 * r + 1.42151175831644588870e-7) * r
                         + 1.84631831751005468180e-5) * r + 7.86869131145613259100e-4) * r
                         + 1.48753612908506148525e-2) * r + 1.36929880922735805310e-1) * r
                         + 5.99832206555887937690e-1) * r + 1.0);
        v = num / den;
    }
    return (q < 0.0) ? -v : v;
}

// ---------------- K0: lsew[d] = logsumexp_n kde_weights[n,d] (block per d) ----------------
__global__ __launch_bounds__(256) void k_lsew(const float* __restrict__ kw,
                                              float* __restrict__ lsew) {
    __shared__ float red[4];
    int d = blockIdx.x;
    int n = threadIdx.x;          // NP == 256 == blockDim
    float a = kw[n * DD + d];
    float m = a;
    #pragma unroll
    for (int off = 32; off; off >>= 1) m = fmaxf(m, __shfl_xor(m, off, 64));
    if ((threadIdx.x & 63) == 0) red[threadIdx.x >> 6] = m;
    __syncthreads();
    m = fmaxf(fmaxf(red[0], red[1]), fmaxf(red[2], red[3]));
    __syncthreads();
    float e = __expf(a - m);
    #pragma unroll
    for (int off = 32; off; off >>= 1) e += __shfl_xor(e, off, 64);
    if ((threadIdx.x & 63) == 0) red[threadIdx.x >> 6] = e;
    __syncthreads();
    if (threadIdx.x == 0)
        lsew[d] = m + __logf(red[0] + red[1] + red[2] + red[3]);
}

// ---------------- K1: per-(n,d) precompute, packed float4 {dp, 1/hs, w, w-lhc} ----------------
__global__ __launch_bounds__(256) void k_prep(const float* __restrict__ kw,
                                              const float* __restrict__ log_hs,
                                              const float* __restrict__ dp,
                                              const float* __restrict__ lsew,
                                              float4* __restrict__ pk) {
    int n = blockIdx.x;
    for (int d = threadIdx.x; d < DD; d += 256) {
        int idx = n * DD + d;
        float lh = log_hs[idx];
        float hs = fmaxf(__expf(lh), HS_MIN);
        float lhc = fmaxf(lh, LOG_HS_MIN);
        float wv = kw[idx] - lsew[d];
        pk[idx] = make_float4(dp[idx], 1.f / hs, wv, wv - lhc);
    }
}

// ---------------- K2: main KDE + inverse + term (BK batch rows / thread) ----------------
__global__ __launch_bounds__(128) void k_main(const float* __restrict__ x,
                                              const float4* __restrict__ pk,
                                              float* __restrict__ Y,
                                              float* __restrict__ T) {
    int g = blockIdx.x * 128 + threadIdx.x;        // g < (BB/BK)*DD exactly
    int d = g % DD;
    int b0 = (g / DD) * BK;
    float xv[BK], m1[BK], s1[BK], m2[BK], s2[BK], m3[BK], s3[BK];
    #pragma unroll
    for (int i = 0; i < BK; ++i) {
        xv[i] = x[(b0 + i) * DD + d];
        m1[i] = -INFINITY; s1[i] = 0.f;
        m2[i] = -INFINITY; s2[i] = 0.f;
        m3[i] = -INFINITY; s3[i] = 0.f;
    }
    for (int n = 0; n < NP; ++n) {
        float4 c = pk[n * DD + d];          // {dp, ihs, w, w-lhc}
        #pragma unroll
        for (int i = 0; i < BK; ++i) {
            float u = (c.x - xv[i]) * c.y;
            float e = __expf(-fabsf(u));
            float l1p = __logf(1.f + e);
            float sp = fmaxf(u, 0.f) + l1p;
            float a1 = c.z - sp;
            float a2 = fminf(u, 0.f) - l1p + c.z;
            float a3 = u - 2.f * sp + c.w;
            // 1-exp online LSE update — bit-identical to the 2-exp form
            float d1 = a1 - m1[i]; float E1 = __expf(-fabsf(d1));
            s1[i] = (d1 <= 0.f) ? (s1[i] + E1) : (s1[i] * E1 + 1.f);
            m1[i] = fmaxf(m1[i], a1);
            float d2 = a2 - m2[i]; float E2 = __expf(-fabsf(d2));
            s2[i] = (d2 <= 0.f) ? (s2[i] + E2) : (s2[i] * E2 + 1.f);
            m2[i] = fmaxf(m2[i], a2);
            float d3 = a3 - m3[i]; float E3 = __expf(-fabsf(d3));
            s3[i] = (d3 <= 0.f) ? (s3[i] + E3) : (s3[i] * E3 + 1.f);
            m3[i] = fmaxf(m3[i], a3);
        }
    }
    #pragma unroll
    for (int i = 0; i < BK; ++i) {
        float log_cdf = m1[i] + __logf(s1[i]);
        float log_sf  = m2[i] + __logf(s2[i]);
        float log_pdf = m3[i] + __logf(s3[i]);
        bool right = (log_sf  <= LOG_MB);
        bool left  = (log_cdf <= LOG_MB);
        float inv, lgd;
        if (right) {
            float t2 = -2.f * log_sf;
            inv = sqrtf(t2);
            lgd = 0.5f * __logf(t2) - log_sf;
        } else if (left) {
            float t2 = -2.f * log_cdf;
            inv = -sqrtf(t2);
            lgd = 0.5f * __logf(t2) - log_cdf;
        } else {
            inv = (float)ndtri_logs(log_cdf, log_sf);
            lgd = -0.5f * inv * inv + NEG_HALF_LOG_2PI;
        }
        Y[(b0 + i) * DD + d] = inv;
        T[(b0 + i) * DD + d] = log_pdf - lgd;
    }
}

// ---------------- K3: log_det reduction ----------------
__global__ __launch_bounds__(256) void k_logdet(const float* __restrict__ T,
                                                const float* __restrict__ ld_in,
                                                float* __restrict__ out) {
    __shared__ float red[4];
    int b = blockIdx.x;
    float s = 0.f;
    for (int d = threadIdx.x; d < DD; d += 256) s += T[b * DD + d];
    #pragma unroll
    for (int off = 32; off; off >>= 1) s += __shfl_down(s, off, 64);
    if ((threadIdx.x & 63) == 0) red[threadIdx.x >> 6] = s;
    __syncthreads();
    if (threadIdx.x == 0) out[BB * DD + b] = ld_in[b] + red[0] + red[1] + red[2] + red[3];
}

// ---------------- K4: normalize reflector rows ----------------
__global__ __launch_bounds__(256) void k_vn(const float* __restrict__ vs,
                                            float* __restrict__ vn) {
    __shared__ float red[4];
    int i = blockIdx.x;
    float ss = 0.f;
    for (int j = threadIdx.x; j < DD; j += 256) {
        float v = vs[i * DD + j];
        ss += v * v;
    }
    #pragma unroll
    for (int off = 32; off; off >>= 1) ss += __shfl_down(ss, off, 64);
    if ((threadIdx.x & 63) == 0) red[threadIdx.x >> 6] = ss;
    __syncthreads();
    float inorm = rsqrtf(red[0] + red[1] + red[2] + red[3]);
    for (int j = threadIdx.x; j < DD; j += 256)
        vn[i * DD + j] = vs[i * DD + j] * inorm;
}

// ---------------- K5: Gram of each 16-reflector window ----------------
__global__ __launch_bounds__(256) void k_gram(const float* __restrict__ vn,
                                              float* __restrict__ G) {
    int wi = blockIdx.x;
    int t = threadIdx.x;
    int k = t >> 4, i = t & 15;
    const float4* a = (const float4*)(vn + (wi * W + k) * DD);
    const float4* b = (const float4*)(vn + (wi * W + i) * DD);
    float s = 0.f;
    for (int j = 0; j < DD / 4; ++j) {
        float4 av = a[j], bv = b[j];
        s += av.x * bv.x + av.y * bv.y + av.z * bv.z + av.w * bv.w;
    }
    G[wi * 256 + k * 16 + i] = s;   // G[w][k][i] = v_k . v_i
}

// ---------------- K6: windowed-WY Householder chain — wave-autonomous ----------------
// One 64-lane wave per batch row; lane owns 12 contiguous cols (+1 extra for
// lanes<16: 784 = 64*12 + 16). V read directly from global (L2-resident) per
// phase — NO staging buffers at all. Three rounds of evidence (VGPR 76/132/84,
// round-6 scratch WRITE_SIZE 6.6MB) show the allocator spills any large staging
// array held across phases; live state here is ~45 floats, statically indexed.
// Reduce + substitution are the green round-2/3 code collapsed to one wave.
__global__ __launch_bounds__(64) void k_house(const float* __restrict__ Yin,
                                              const float* __restrict__ VN,
                                              const float* __restrict__ G,
                                              float* __restrict__ out) {
    __shared__ float s2s[W];
    const int b = blockIdx.x;
    const int lane = threadIdx.x;        // 64 threads = exactly one wave
    const int cb = lane * 12;            // 12 contiguous cols; 48B offset = float4-aligned
    const bool xtra = (lane < 16);       // also owns col 768+lane

    const float* yrow = Yin + b * DD;
    float4 y0 = *(const float4*)(yrow + cb);
    float4 y1 = *(const float4*)(yrow + cb + 4);
    float4 y2 = *(const float4*)(yrow + cb + 8);
    float yx = xtra ? yrow[768 + lane] : 0.f;

    for (int wi = 0; wi < NW; ++wi) {
        // G column for the substitution (lanes<16)
        float Gcol[W];
        #pragma unroll
        for (int k = 0; k < W; ++k)
            Gcol[k] = xtra ? G[wi * 256 + k * 16 + lane] : 0.f;

        // dots: p[r] = partial q_r over this lane's 12(+1) cols
        float p[W];
        #pragma unroll
        for (int r = 0; r < W; ++r) {
            const float* vrow = VN + (wi * W + r) * DD;
            float4 a = *(const float4*)(vrow + cb);
            float4 c = *(const float4*)(vrow + cb + 4);
            float4 e = *(const float4*)(vrow + cb + 8);
            float vx = xtra ? vrow[768 + lane] : 0.f;
            p[r] = y0.x*a.x + y0.y*a.y + y0.z*a.z + y0.w*a.w
                 + y1.x*c.x + y1.y*c.y + y1.z*c.z + y1.w*c.w
                 + y2.x*e.x + y2.y*e.y + y2.z*e.z + y2.w*e.w
                 + yx * vx;
        }

        // wave butterfly reduce (green round-2/3 verbatim)
        #pragma unroll
        for (int r = 0; r < W; ++r) {
            #pragma unroll
            for (int off = 32; off; off >>= 1)
                p[r] += __shfl_xor(p[r], off, 64);
        }
        float mine = p[0];
        #pragma unroll
        for (int r = 1; r < W; ++r)
            if (lane == r) mine = p[r];

        // forward substitution s_r = q_r - 2 sum_{k<r} G[k][r] s_k (green, 1 wave)
        float acc = xtra ? mine : 0.f;
        #pragma unroll
        for (int k = 0; k < W; ++k) {
            float sk = __shfl(acc, k, 64);
            if (lane > k) acc -= 2.f * Gcol[k] * sk;
        }
        if (xtra) s2s[lane] = 2.f * acc;
        __syncthreads();   // single-wave barrier: cheap, orders s2s

        // rank-16 update (V re-read from L2 — no registers held across phases)
        #pragma unroll
        for (int r = 0; r < W; ++r) {
            float s2 = s2s[r];
            const float* vrow = VN + (wi * W + r) * DD;
            float4 a = *(const float4*)(vrow + cb);
            float4 c = *(const float4*)(vrow + cb + 4);
            float4 e = *(const float4*)(vrow + cb + 8);
            y0.x -= s2*a.x; y0.y -= s2*a.y; y0.z -= s2*a.z; y0.w -= s2*a.w;
            y1.x -= s2*c.x; y1.y -= s2*c.y; y1.z -= s2*c.z; y1.w -= s2*c.w;
            y2.x -= s2*e.x; y2.y -= s2*e.y; y2.z -= s2*e.z; y2.w -= s2*e.w;
            if (xtra) yx -= s2 * vrow[768 + lane];
        }
        __syncthreads();   // protect s2s before next window's write
    }

    float* orow = out + b * DD;
    *(float4*)(orow + cb)     = y0;
    *(float4*)(orow + cb + 4) = y1;
    *(float4*)(orow + cb + 8) = y2;
    if (xtra) orow[768 + lane] = yx;
}

// ---------------- launch ----------------
extern "C" void kernel_launch(void* const* d_in, const int* in_sizes, int n_in,
                              void* d_out, int out_size, void* d_ws, size_t ws_size,
                              hipStream_t stream) {
    const float* x      = (const float*)d_in[0];   // [B,D]
    const float* ld_in  = (const float*)d_in[1];   // [B]
    const float* dp     = (const float*)d_in[2];   // [N,D]
    const float* log_hs = (const float*)d_in[3];   // [N,D]
    const float* kw     = (const float*)d_in[4];   // [N,D]
    const float* vs     = (const float*)d_in[5];   // [D,D]
    float* out = (float*)d_out;                    // x_out [B,D] then log_det [B]

    float* ws   = (float*)d_ws;
    float* lsew = ws;                         // 784 (pad to 1024)
    float4* pk  = (float4*)(ws + 1024);       // N*D float4
    float* Y    = ws + 1024 + NP * DD * 4;    // B*D
    float* T    = Y + BB * DD;                // B*D
    float* VN   = T + BB * DD;                // D*D
    float* G    = VN + DD * DD;               // NW*256

    k_lsew<<<DD, 256, 0, stream>>>(kw, lsew);
    k_prep<<<NP, 256, 0, stream>>>(kw, log_hs, dp, lsew, pk);
    k_main<<<(BB / BK) * DD / 128, 128, 0, stream>>>(x, pk, Y, T);
    k_logdet<<<BB, 256, 0, stream>>>(T, ld_in, out);
    k_vn<<<DD, 256, 0, stream>>>(vs, VN);
    k_gram<<<NW, 256, 0, stream>>>(VN, G);
    k_house<<<BB, 64, 0, stream>>>(Y, VN, G, out);
}